// Round 2
// baseline (1211.676 us; speedup 1.0000x reference)
//
#include <hip/hip_runtime.h>
#include <cstdint>
#include <cmath>

#define NB 8192
#define ND 128
#define CAP 64
#define NEG_INF (-__builtin_inff())

typedef __attribute__((ext_vector_type(8))) __bf16 bf16x8;
typedef __attribute__((ext_vector_type(2))) __bf16 bf16x2;
typedef __attribute__((ext_vector_type(4))) float f32x4;

// Insert v into ascending top-K list (identity when v <= t[0]).
__device__ __forceinline__ void insert10(float t[10], float v) {
#pragma unroll
  for (int j = 0; j < 9; ++j) t[j] = __builtin_amdgcn_fmed3f(t[j], t[j + 1], v);
  t[9] = fmaxf(t[9], v);
}
__device__ __forceinline__ void insert11(float t[11], float v) {
#pragma unroll
  for (int j = 0; j < 10; ++j) t[j] = __builtin_amdgcn_fmed3f(t[j], t[j + 1], v);
  t[10] = fmaxf(t[10], v);
}

// ---------------------------------------------------------------------------
// Row loss via column-10-only soft sort (P row-stochastic => p_neg = 1-p_pos,
// clips no-ops, both BCEs identical). Verified exact (absmax 0.0).
// ---------------------------------------------------------------------------
__device__ float row_loss(float x[11]) {
  float al[55];
#pragma unroll
  for (int layer = 0; layer < 11; ++layer) {
#pragma unroll
    for (int p = 0; p < 5; ++p) {
      int ii = (layer & 1) + 2 * p;
      float av = x[ii], bv = x[ii + 1];
      float a = atanf(bv - av) * 0.3183098861837907f + 0.5f;
      al[layer * 5 + p] = a;
      float be = 1.f - a;
      x[ii] = a * av + be * bv;
      x[ii + 1] = be * av + a * bv;
    }
  }
  float v[11];
#pragma unroll
  for (int i = 0; i < 11; ++i) v[i] = 0.f;
  v[10] = 1.f;
#pragma unroll
  for (int layer = 10; layer >= 0; --layer) {
#pragma unroll
    for (int p = 0; p < 5; ++p) {
      int ii = (layer & 1) + 2 * p;
      float a = al[layer * 5 + p];
      float be = 1.f - a;
      float va = v[ii], vb = v[ii + 1];
      v[ii] = a * va + be * vb;
      v[ii + 1] = be * va + a * vb;
    }
  }
  float C = fmaxf(logf(v[10]), -100.f);
#pragma unroll
  for (int i = 0; i < 10; ++i) C += fmaxf(logf(1.f - v[i]), -100.f);
  return C;
}

// ---------------------------------------------------------------------------
// Kernel 1: row-normalize -> bf16 + fp32 pos_sims. Block 0 zeroes d_out
// (kernel-boundary ordering on the stream makes this visible to ksort).
// ---------------------------------------------------------------------------
__global__ __launch_bounds__(256, 4) void knorm(const float* __restrict__ aug1,
                                                const float* __restrict__ aug2,
                                                __bf16* __restrict__ an,
                                                float* __restrict__ pos,
                                                float* __restrict__ out) {
  if (blockIdx.x == 0 && threadIdx.x == 0) out[0] = 0.f;
  int wid = threadIdx.x >> 6;
  int l = threadIdx.x & 63;
  int row = blockIdx.x * 4 + wid;
  const float2* a1 = (const float2*)(aug1) + (size_t)row * 64;
  const float2* a2 = (const float2*)(aug2) + (size_t)row * 64;
  float2 v1 = a1[l], v2 = a2[l];
  float ss1 = v1.x * v1.x + v1.y * v1.y;
  float ss2 = v2.x * v2.x + v2.y * v2.y;
  float dp = v1.x * v2.x + v1.y * v2.y;
#pragma unroll
  for (int off = 1; off < 64; off <<= 1) {
    ss1 += __shfl_xor(ss1, off);
    ss2 += __shfl_xor(ss2, off);
    dp += __shfl_xor(dp, off);
  }
  float inv1 = 1.0f / fmaxf(sqrtf(ss1), 1e-8f);
  float inv2 = 1.0f / fmaxf(sqrtf(ss2), 1e-8f);
  bf16x2 o1, o2;
  o1[0] = (__bf16)(v1.x * inv1);
  o1[1] = (__bf16)(v1.y * inv1);
  o2[0] = (__bf16)(v2.x * inv2);
  o2[1] = (__bf16)(v2.y * inv2);
  ((bf16x2*)(an))[(size_t)row * 64 + l] = o1;
  ((bf16x2*)(an + (size_t)NB * ND))[(size_t)row * 64 + l] = o2;
  if (l == 0) pos[row] = dp * inv1 * inv2;
}

// Unconditional (no diag mask) survivor append to per-row LDS buffers.
__device__ __forceinline__ void consume4(const f32x4* acc, float (*cand)[CAP],
                                         int* lcnt, float tau, int c) {
#pragma unroll
  for (int rb = 0; rb < 4; ++rb) {
    int rl = rb * 16 + c;
#pragma unroll
    for (int r = 0; r < 4; ++r) {
      float v = acc[rb][r];
      if (v > tau) {
        int s = atomicAdd(&lcnt[rl], 1);
        if (s < CAP) cand[rl][s] = v;
      }
    }
  }
}

// ---------------------------------------------------------------------------
// Kernel 2: fused Gram + self-calibrating threshold filter. 2-way column
// split (proven config: 512 blocks, R1's 4-way split regressed -- occupancy
// was not the limiter). Software pipeline now distance-2 for BOTH fragment
// buffers: loadA2(t+3) is issued a full pair-iteration before its consuming
// mfma_tile (was loadA2(t+1), covered only by ~100cy of consume4 -> exposed
// L2 latency stall every iteration, the MfmaUtil~16% signature).
// Diagonal handled in epilogue: self-sim (=1.0, always > tau) is the max
// candidate; the diag-containing block keeps top-11 and drops the max.
// Counts/taus written unconditionally -> no memset needed.
// ---------------------------------------------------------------------------
__global__ __launch_bounds__(256, 3) void kgram(const __bf16* __restrict__ an_all,
                                                float* __restrict__ tk,
                                                int* __restrict__ cnth,
                                                float* __restrict__ taug) {
  int dir = blockIdx.y;
  int rowg = blockIdx.x >> 1;
  int half = blockIdx.x & 1;
  const bf16x8* an8 = (const bf16x8*)(an_all + (size_t)dir * NB * ND);
  int w = threadIdx.x >> 6;
  int l = threadIdx.x & 63;
  int q = l >> 4;
  int c = l & 15;
  int row_base = rowg * 64;
  const int col0 = half * 4096;

  __shared__ float cand[64][CAP];
  __shared__ int lcnt[64];
  __shared__ float sred[2][4];
  if (threadIdx.x < 64) lcnt[threadIdx.x] = 0;

  // Row fragments (B-operand), resident all kernel (compiler -> AGPRs).
  bf16x8 brow[4][4];
#pragma unroll
  for (int rb = 0; rb < 4; ++rb)
#pragma unroll
    for (int kc = 0; kc < 4; ++kc)
      brow[rb][kc] = an8[(size_t)(row_base + rb * 16 + c) * 16 + kc * 4 + q];

  const bf16x8* pf0 = an8 + ((size_t)(col0 + w * 16 + c) * 16 + q);
  bf16x8 a[4], a2[4];
  const f32x4 zz = {0.f, 0.f, 0.f, 0.f};
  f32x4 accA[4], accB[4];

  auto loadA = [&](int t) {  // tile t -> a
    const bf16x8* p = pf0 + (size_t)(t & 63) * 1024;
#pragma unroll
    for (int kc = 0; kc < 4; ++kc) a[kc] = p[kc * 4];
  };
  auto loadA2 = [&](int t) {  // tile t -> a2
    const bf16x8* p = pf0 + (size_t)(t & 63) * 1024;
#pragma unroll
    for (int kc = 0; kc < 4; ++kc) a2[kc] = p[kc * 4];
  };
  auto mfma_tile = [&](f32x4* A, const bf16x8* src) {
#pragma unroll
    for (int rb = 0; rb < 4; ++rb)
      A[rb] = __builtin_amdgcn_mfma_f32_16x16x32_bf16(src[0], brow[rb][0], zz, 0, 0, 0);
#pragma unroll
    for (int kc = 1; kc < 4; ++kc)
#pragma unroll
      for (int rb = 0; rb < 4; ++rb)
        A[rb] = __builtin_amdgcn_mfma_f32_16x16x32_bf16(src[kc], brow[rb][kc], A[rb], 0, 0, 0);
  };

  // ---- prologue: tiles 0..3 in flight; stats (diag-masked) + tau on t0 ----
  loadA(0);
  loadA2(1);
  mfma_tile(accA, a);   // t0 (a free after; a2 still in flight)
  loadA(2);             // a <- t2, full-iteration cover
  bool diag0 = (row_base == col0);
  int cq0 = col0 + w * 16 + q * 4;
  float s1 = 0.f, s2 = 0.f;
#pragma unroll
  for (int rb = 0; rb < 4; ++rb) {
    int myrow = row_base + rb * 16 + c;
#pragma unroll
    for (int r = 0; r < 4; ++r) {
      float v = accA[rb][r];
      v = (diag0 && (cq0 + r == myrow)) ? 0.f : v;
      s1 += v;
      s2 = fmaf(v, v, s2);
    }
  }
#pragma unroll
  for (int off = 1; off < 64; off <<= 1) {
    s1 += __shfl_xor(s1, off);
    s2 += __shfl_xor(s2, off);
  }
  if (l == 0) { sred[0][w] = s1; sred[1][w] = s2; }
  __syncthreads();
  float n = diag0 ? 4032.f : 4096.f;
  float ts1 = sred[0][0] + sred[0][1] + sred[0][2] + sred[0][3];
  float ts2 = sred[1][0] + sred[1][1] + sred[1][2] + sred[1][3];
  float mu = ts1 / n;
  float sig = sqrtf(fmaxf(ts2 / n - mu * mu, 0.f));
  float tau = mu + 2.5f * sig;  // lambda ~25 survivors per row-half
  if (threadIdx.x == 0) taug[(dir * 128 + rowg) * 2 + half] = tau;
  consume4(accA, cand, lcnt, tau, c);  // t0

  mfma_tile(accA, a2);  // t1 (a2 free after)
  loadA2(3);            // a2 <- t3

  // ---- steady state: pairs (2,3),(4,5),...,(62,63), dist-2 prefetch ----
  for (int t = 2; t < 64; t += 2) {
    mfma_tile(accB, a);                 // tile t (a free after)
    loadA(t + 2);                       // a <- t+2 (wraps harmlessly at 62)
    consume4(accA, cand, lcnt, tau, c); // tile t-1 (overlaps accB MFMAs)
    mfma_tile(accA, a2);                // tile t+1 (a2 free after)
    loadA2(t + 3);                      // a2 <- t+3 (wraps harmlessly at 62)
    consume4(accB, cand, lcnt, tau, c); // tile t
  }
  consume4(accA, cand, lcnt, tau, c);   // tile 63

  // ---- epilogue: per-row top-11, drop max if this block holds the diag ----
  __syncthreads();
  if (threadIdx.x < 64) {
    int rl = threadIdx.x;
    int cc = lcnt[rl];
    float t11[11];
#pragma unroll
    for (int j = 0; j < 11; ++j) t11[j] = NEG_INF;
    int m = cc < CAP ? cc : CAP;
    for (int i = 0; i < m; ++i) {
      float v = cand[rl][i];
      if (v > t11[0]) insert11(t11, v);
    }
    bool diagq = (row_base >= col0) && (row_base < col0 + 4096);
    float* o = tk + ((size_t)(dir * NB + row_base + rl) * 2 + half) * 10;
    if (diagq) {  // t11[10] is the self-sim (max) -> drop it
#pragma unroll
      for (int j = 0; j < 10; ++j) o[j] = t11[j];
    } else {      // keep the 10 largest
#pragma unroll
      for (int j = 0; j < 10; ++j) o[j] = t11[j + 1];
    }
    cnth[(dir * NB + row_base + rl) * 2 + half] = cc;
  }
}

// ---------------------------------------------------------------------------
// Kernel 3: merge half-lists, tau-proof, soft-sort + BCE; exact brute-force
// fallback for unproven rows (statistically never fires).
// ---------------------------------------------------------------------------
__global__ __launch_bounds__(64, 1) void ksort(const float* __restrict__ tk,
                                               const float* __restrict__ pos,
                                               const int* __restrict__ cnth,
                                               const float* __restrict__ taug,
                                               const __bf16* __restrict__ an_all,
                                               float* __restrict__ out) {
  int tid = blockIdx.x * 64 + threadIdx.x;
  int dir = tid >> 13;
  int row = tid & (NB - 1);
  int lane = threadIdx.x;

  const float* A = tk + (size_t)(dir * NB + row) * 20;
  float s10[10];
#pragma unroll
  for (int j = 0; j < 10; ++j) s10[j] = A[j];
#pragma unroll
  for (int j = 0; j < 10; ++j) {
    float v = A[10 + j];
    if (v > s10[0]) insert10(s10, v);
  }
  int rowg = row >> 6;
  float tmax = fmaxf(taug[(dir * 128 + rowg) * 2], taug[(dir * 128 + rowg) * 2 + 1]);
  int2 cc2 = ((const int2*)cnth)[dir * NB + row];
  // Proof: every unreported sim is <= its half's tau <= tmax <= s10[0], and
  // no half overflowed CAP -> s10 is the exact top-10.
  bool ok = (cc2.x <= CAP) && (cc2.y <= CAP) && (s10[0] >= tmax);

  float C = 0.f;
  if (ok) {
    float x[11];
#pragma unroll
    for (int j = 0; j < 10; ++j) x[j] = s10[j];
    x[10] = pos[row];
    C = row_loss(x);
  }
#pragma unroll
  for (int off = 1; off < 64; off <<= 1) C += __shfl_xor(C, off);
  if (lane == 0) atomicAdd(out, C * (-1.f / (2.f * (float)NB * 11.f)));

  unsigned long long bad = __ballot(!ok);
  if (bad == 0ull) return;
  __shared__ float rv[128];
  __shared__ float lst[64][10];
  const __bf16* an = an_all + (size_t)dir * NB * ND;
  while (bad) {
    int b = __ffsll((long long)bad) - 1;
    bad &= bad - 1;
    int brow = (blockIdx.x * 64 + b) & (NB - 1);
    bf16x2 pr = ((const bf16x2*)an)[(size_t)brow * 64 + lane];
    rv[lane * 2] = (float)pr[0];
    rv[lane * 2 + 1] = (float)pr[1];
    __syncthreads();
    float t10[10];
#pragma unroll
    for (int j = 0; j < 10; ++j) t10[j] = NEG_INF;
    for (int i = 0; i < 128; ++i) {
      int col = lane + i * 64;
      if (col == brow) continue;
      const bf16x8* cp = (const bf16x8*)(an + (size_t)col * ND);
      float d = 0.f;
#pragma unroll
      for (int k = 0; k < 16; ++k) {
        bf16x8 p = cp[k];
#pragma unroll
        for (int e = 0; e < 8; ++e) d = fmaf(rv[k * 8 + e], (float)p[e], d);
      }
      if (d > t10[0]) insert10(t10, d);
    }
#pragma unroll
    for (int j = 0; j < 10; ++j) lst[lane][j] = t10[j];
    __syncthreads();
    if (lane == 0) {
      float cur[10];
#pragma unroll
      for (int j = 0; j < 10; ++j) cur[j] = lst[0][j];
      for (int s = 1; s < 64; ++s)
        for (int j = 0; j < 10; ++j) {
          float v = lst[s][j];
          if (v > cur[0]) insert10(cur, v);
        }
      float x[11];
#pragma unroll
      for (int j = 0; j < 10; ++j) x[j] = cur[j];
      x[10] = pos[brow];
      atomicAdd(out, row_loss(x) * (-1.f / (2.f * (float)NB * 11.f)));
    }
    __syncthreads();
  }
}

// ---------------------------------------------------------------------------
// ws: [an bf16 4MB][pos 32KB][tk 1.31MB][cnth 128KB][taug 2KB]. 3 nodes, no
// memsets: knorm zeroes d_out; cnth/taug written unconditionally by kgram.
// ---------------------------------------------------------------------------
extern "C" void kernel_launch(void* const* d_in, const int* in_sizes, int n_in,
                              void* d_out, int out_size, void* d_ws, size_t ws_size,
                              hipStream_t stream) {
  const float* aug1 = (const float*)d_in[0];
  const float* aug2 = (const float*)d_in[1];
  char* w = (char*)d_ws;
  __bf16* an = (__bf16*)w;
  float* pos = (float*)(w + (size_t)4 * 1024 * 1024);
  float* tk = pos + NB;
  int* cnth = (int*)(tk + (size_t)2 * NB * 20);
  float* taug = (float*)(cnth + 2 * NB * 2);

  knorm<<<dim3(NB / 4), dim3(256), 0, stream>>>(aug1, aug2, an, pos, (float*)d_out);
  kgram<<<dim3(256, 2), dim3(256), 0, stream>>>(an, tk, cnth, taug);
  ksort<<<dim3(2 * NB / 64), dim3(64), 0, stream>>>(tk, pos, cnth, taug, an, (float*)d_out);
}

// Round 3
// 157.553 us; speedup vs baseline: 7.6906x; 7.6906x over previous
//
#include <hip/hip_runtime.h>
#include <cstdint>
#include <cmath>

#define NB 8192
#define ND 128
#define CAP 64
#define CAPP 65  // padded cand stride: bank = (rl+i)%32 -> conflict-free epilogue
#define NEG_INF (-__builtin_inff())

typedef __attribute__((ext_vector_type(8))) __bf16 bf16x8;
typedef __attribute__((ext_vector_type(2))) __bf16 bf16x2;
typedef __attribute__((ext_vector_type(4))) float f32x4;

// Insert v into ascending top-K list (identity when v <= t[0]).
__device__ __forceinline__ void insert10(float t[10], float v) {
#pragma unroll
  for (int j = 0; j < 9; ++j) t[j] = __builtin_amdgcn_fmed3f(t[j], t[j + 1], v);
  t[9] = fmaxf(t[9], v);
}
__device__ __forceinline__ void insert11(float t[11], float v) {
#pragma unroll
  for (int j = 0; j < 10; ++j) t[j] = __builtin_amdgcn_fmed3f(t[j], t[j + 1], v);
  t[10] = fmaxf(t[10], v);
}

// ---------------------------------------------------------------------------
// Row loss via column-10-only soft sort (P row-stochastic => p_neg = 1-p_pos,
// clips no-ops, both BCEs identical). Verified exact (absmax 0.0).
// ---------------------------------------------------------------------------
__device__ float row_loss(float x[11]) {
  float al[55];
#pragma unroll
  for (int layer = 0; layer < 11; ++layer) {
#pragma unroll
    for (int p = 0; p < 5; ++p) {
      int ii = (layer & 1) + 2 * p;
      float av = x[ii], bv = x[ii + 1];
      float a = atanf(bv - av) * 0.3183098861837907f + 0.5f;
      al[layer * 5 + p] = a;
      float be = 1.f - a;
      x[ii] = a * av + be * bv;
      x[ii + 1] = be * av + a * bv;
    }
  }
  float v[11];
#pragma unroll
  for (int i = 0; i < 11; ++i) v[i] = 0.f;
  v[10] = 1.f;
#pragma unroll
  for (int layer = 10; layer >= 0; --layer) {
#pragma unroll
    for (int p = 0; p < 5; ++p) {
      int ii = (layer & 1) + 2 * p;
      float a = al[layer * 5 + p];
      float be = 1.f - a;
      float va = v[ii], vb = v[ii + 1];
      v[ii] = a * va + be * vb;
      v[ii + 1] = be * va + a * vb;
    }
  }
  float C = fmaxf(logf(v[10]), -100.f);
#pragma unroll
  for (int i = 0; i < 10; ++i) C += fmaxf(logf(1.f - v[i]), -100.f);
  return C;
}

// ---------------------------------------------------------------------------
// Kernel 1: row-normalize -> bf16 + fp32 pos_sims. Block 0 zeroes d_out
// (kernel-boundary ordering on the stream makes this visible to ksort).
// ---------------------------------------------------------------------------
__global__ __launch_bounds__(256, 4) void knorm(const float* __restrict__ aug1,
                                                const float* __restrict__ aug2,
                                                __bf16* __restrict__ an,
                                                float* __restrict__ pos,
                                                float* __restrict__ out) {
  if (blockIdx.x == 0 && threadIdx.x == 0) out[0] = 0.f;
  int wid = threadIdx.x >> 6;
  int l = threadIdx.x & 63;
  int row = blockIdx.x * 4 + wid;
  const float2* a1 = (const float2*)(aug1) + (size_t)row * 64;
  const float2* a2 = (const float2*)(aug2) + (size_t)row * 64;
  float2 v1 = a1[l], v2 = a2[l];
  float ss1 = v1.x * v1.x + v1.y * v1.y;
  float ss2 = v2.x * v2.x + v2.y * v2.y;
  float dp = v1.x * v2.x + v1.y * v2.y;
#pragma unroll
  for (int off = 1; off < 64; off <<= 1) {
    ss1 += __shfl_xor(ss1, off);
    ss2 += __shfl_xor(ss2, off);
    dp += __shfl_xor(dp, off);
  }
  float inv1 = 1.0f / fmaxf(sqrtf(ss1), 1e-8f);
  float inv2 = 1.0f / fmaxf(sqrtf(ss2), 1e-8f);
  bf16x2 o1, o2;
  o1[0] = (__bf16)(v1.x * inv1);
  o1[1] = (__bf16)(v1.y * inv1);
  o2[0] = (__bf16)(v2.x * inv2);
  o2[1] = (__bf16)(v2.y * inv2);
  ((bf16x2*)(an))[(size_t)row * 64 + l] = o1;
  ((bf16x2*)(an + (size_t)NB * ND))[(size_t)row * 64 + l] = o2;
  if (l == 0) pos[row] = dp * inv1 * inv2;
}

// Unconditional (no diag mask) survivor append to per-row LDS buffers.
__device__ __forceinline__ void consume4(const f32x4* acc, float (*cand)[CAPP],
                                         int* lcnt, float tau, int c) {
#pragma unroll
  for (int rb = 0; rb < 4; ++rb) {
    int rl = rb * 16 + c;
#pragma unroll
    for (int r = 0; r < 4; ++r) {
      float v = acc[rb][r];
      if (v > tau) {
        int s = atomicAdd(&lcnt[rl], 1);
        if (s < CAP) cand[rl][s] = v;
      }
    }
  }
}

// ---------------------------------------------------------------------------
// Kernel 2: fused Gram + self-calibrating threshold filter, restructured as
// the proven LDS-staged 2-phase pipeline (guide T3 minimum recipe):
//   stage(t+1) via global_load_lds (width=16, async DMA) -> ds_read frags of
//   tile t -> MFMA -> consume -> __syncthreads (== vmcnt(0)+barrier).
// R0-R2 evidence: register-direct scattered loads pinned MfmaUtil at ~16%
// regardless of occupancy (R1) or prefetch distance (R2) -- the m97-ceiling
// signature. LDS tile is XOR-swizzled BOTH sides (rule #21): linear LDS dest,
// pre-swizzled global source unit ^= col&7, identically-swizzled ds_read ->
// 2 lanes/bank (free). Bytes to each MFMA bit-identical to R0 => absmax 0.0.
// Diagonal handled in epilogue: self-sim (=1.0, always > tau) is the max
// candidate; the diag-containing block keeps top-11 and drops the max.
// ---------------------------------------------------------------------------
__global__ __launch_bounds__(256, 2) void kgram(const __bf16* __restrict__ an_all,
                                                float* __restrict__ tk,
                                                int* __restrict__ cnth,
                                                float* __restrict__ taug) {
  int dir = blockIdx.y;
  int rowg = blockIdx.x >> 1;
  int half = blockIdx.x & 1;
  const __bf16* an = an_all + (size_t)dir * NB * ND;
  const bf16x8* an8 = (const bf16x8*)an;
  int w = threadIdx.x >> 6;
  int l = threadIdx.x & 63;
  int q = l >> 4;
  int c = l & 15;
  int row_base = rowg * 64;
  const int col0 = half * 4096;

  __shared__ char sbuf[2][16384];  // double-buffered 64col x 256B tile
  __shared__ float cand[64][CAPP];
  __shared__ int lcnt[64];
  __shared__ float sred[2][4];
  if (threadIdx.x < 64) lcnt[threadIdx.x] = 0;

  // Row fragments (B-operand), resident all kernel (compiler -> AGPRs).
  // One-time scattered global loads; latency amortized.
  bf16x8 brow[4][4];
#pragma unroll
  for (int rb = 0; rb < 4; ++rb)
#pragma unroll
    for (int kc = 0; kc < 4; ++kc)
      brow[rb][kc] = an8[(size_t)(row_base + rb * 16 + c) * 16 + kc * 4 + q];

  // ---- staging: tile t = 16KB contiguous at panel + t*16384. Wave w DMAs
  // its 4KB quarter (cols w*16+k*4+q, LDS unit u=c) with source unit
  // pre-swizzled: src_unit = c ^ ((k*4+q)&7) = c ^ q ^ (4*(k&1)).
  const char* panel = (const char*)an + (size_t)col0 * 256;
  const int seE = (w * 16 + q) * 256 + ((c ^ q) << 4);
  const int seO = (w * 16 + q) * 256 + (((c ^ q) ^ 4) << 4);
  auto stage = [&](int buf, int t) {
    const char* tb = panel + (size_t)t * 16384;
    char* db = &sbuf[buf][w * 4096];  // wave-uniform dest; HW adds lane*16
#pragma unroll
    for (int k = 0; k < 4; ++k) {
      const char* src = tb + ((k & 1) ? seO : seE) + k * 1024;
      __builtin_amdgcn_global_load_lds(
          (const __attribute__((address_space(1))) void*)src,
          (__attribute__((address_space(3))) void*)(db + k * 1024), 16, 0, 0);
    }
  };

  // ---- fragment reads: LDS[col][u] holds G[col][u ^ (col&7)]; to get
  // G[col][kc*4+q] read u = (kc*4+q) ^ (c&7)  (col = w*16+c, col&7 = c&7).
  int rdo[4];
#pragma unroll
  for (int kc = 0; kc < 4; ++kc)
    rdo[kc] = (w * 16 + c) * 256 + ((((kc * 4 + q) ^ (c & 7))) << 4);
  auto readfr = [&](int buf, bf16x8* a) {
    const char* bp = &sbuf[buf][0];
#pragma unroll
    for (int kc = 0; kc < 4; ++kc) a[kc] = *(const bf16x8*)(bp + rdo[kc]);
  };

  const f32x4 zz = {0.f, 0.f, 0.f, 0.f};
  auto mfma_tile = [&](f32x4* A, const bf16x8* src) {
#pragma unroll
    for (int rb = 0; rb < 4; ++rb)
      A[rb] = __builtin_amdgcn_mfma_f32_16x16x32_bf16(src[0], brow[rb][0], zz, 0, 0, 0);
#pragma unroll
    for (int kc = 1; kc < 4; ++kc)
#pragma unroll
      for (int rb = 0; rb < 4; ++rb)
        A[rb] = __builtin_amdgcn_mfma_f32_16x16x32_bf16(src[kc], brow[rb][kc], A[rb], 0, 0, 0);
  };

  // ---- prologue: tile 0 compute + stats (diag-masked) + tau ----
  stage(0, 0);
  __syncthreads();  // vmcnt(0)+barrier: t0 ready (also covers lcnt init)
  stage(1, 1);      // prefetch t1; completes by the stats barrier below
  bf16x8 a[4];
  f32x4 acc[4];
  readfr(0, a);
  mfma_tile(acc, a);
  bool diag0 = (row_base == col0);
  int cq0 = col0 + w * 16 + q * 4;
  float s1 = 0.f, s2 = 0.f;
#pragma unroll
  for (int rb = 0; rb < 4; ++rb) {
    int myrow = row_base + rb * 16 + c;
#pragma unroll
    for (int r = 0; r < 4; ++r) {
      float v = acc[rb][r];
      v = (diag0 && (cq0 + r == myrow)) ? 0.f : v;
      s1 += v;
      s2 = fmaf(v, v, s2);
    }
  }
#pragma unroll
  for (int off = 1; off < 64; off <<= 1) {
    s1 += __shfl_xor(s1, off);
    s2 += __shfl_xor(s2, off);
  }
  if (l == 0) { sred[0][w] = s1; sred[1][w] = s2; }
  __syncthreads();  // sred ready; t0 reads done; t1 stage drained
  float n = diag0 ? 4032.f : 4096.f;
  float ts1 = sred[0][0] + sred[0][1] + sred[0][2] + sred[0][3];
  float ts2 = sred[1][0] + sred[1][1] + sred[1][2] + sred[1][3];
  float mu = ts1 / n;
  float sig = sqrtf(fmaxf(ts2 / n - mu * mu, 0.f));
  float tau = mu + 2.5f * sig;  // lambda ~25 survivors per row-half
  if (threadIdx.x == 0) taug[(dir * 128 + rowg) * 2 + half] = tau;
  consume4(acc, cand, lcnt, tau, c);  // t0

  // ---- steady state: tiles 1..63, 2-phase double-buffer ----
  for (int t = 1; t < 64; ++t) {
    int cur = t & 1;
    if (t < 63) stage(cur ^ 1, t + 1);  // overwrites tile t-1's buffer (safe:
                                        // its reads completed pre-barrier)
    readfr(cur, a);
    mfma_tile(acc, a);
    consume4(acc, cand, lcnt, tau, c);
    __syncthreads();  // == vmcnt(0)+barrier: stage(t+1) landed, reads done
  }

  // ---- epilogue: per-row top-11, drop max if this block holds the diag ----
  if (threadIdx.x < 64) {
    int rl = threadIdx.x;
    int cc = lcnt[rl];
    float t11[11];
#pragma unroll
    for (int j = 0; j < 11; ++j) t11[j] = NEG_INF;
    int m = cc < CAP ? cc : CAP;
    for (int i = 0; i < m; ++i) {
      float v = cand[rl][i];
      if (v > t11[0]) insert11(t11, v);
    }
    bool diagq = (row_base >= col0) && (row_base < col0 + 4096);
    float* o = tk + ((size_t)(dir * NB + row_base + rl) * 2 + half) * 10;
    if (diagq) {  // t11[10] is the self-sim (max) -> drop it
#pragma unroll
      for (int j = 0; j < 10; ++j) o[j] = t11[j];
    } else {      // keep the 10 largest
#pragma unroll
      for (int j = 0; j < 10; ++j) o[j] = t11[j + 1];
    }
    cnth[(dir * NB + row_base + rl) * 2 + half] = cc;
  }
}

// ---------------------------------------------------------------------------
// Kernel 3: merge half-lists, tau-proof, soft-sort + BCE; exact brute-force
// fallback for unproven rows (statistically never fires).
// ---------------------------------------------------------------------------
__global__ __launch_bounds__(64, 1) void ksort(const float* __restrict__ tk,
                                               const float* __restrict__ pos,
                                               const int* __restrict__ cnth,
                                               const float* __restrict__ taug,
                                               const __bf16* __restrict__ an_all,
                                               float* __restrict__ out) {
  int tid = blockIdx.x * 64 + threadIdx.x;
  int dir = tid >> 13;
  int row = tid & (NB - 1);
  int lane = threadIdx.x;

  const float* A = tk + (size_t)(dir * NB + row) * 20;
  float s10[10];
#pragma unroll
  for (int j = 0; j < 10; ++j) s10[j] = A[j];
#pragma unroll
  for (int j = 0; j < 10; ++j) {
    float v = A[10 + j];
    if (v > s10[0]) insert10(s10, v);
  }
  int rowg = row >> 6;
  float tmax = fmaxf(taug[(dir * 128 + rowg) * 2], taug[(dir * 128 + rowg) * 2 + 1]);
  int2 cc2 = ((const int2*)cnth)[dir * NB + row];
  // Proof: every unreported sim is <= its half's tau <= tmax <= s10[0], and
  // no half overflowed CAP -> s10 is the exact top-10.
  bool ok = (cc2.x <= CAP) && (cc2.y <= CAP) && (s10[0] >= tmax);

  float C = 0.f;
  if (ok) {
    float x[11];
#pragma unroll
    for (int j = 0; j < 10; ++j) x[j] = s10[j];
    x[10] = pos[row];
    C = row_loss(x);
  }
#pragma unroll
  for (int off = 1; off < 64; off <<= 1) C += __shfl_xor(C, off);
  if (lane == 0) atomicAdd(out, C * (-1.f / (2.f * (float)NB * 11.f)));

  unsigned long long bad = __ballot(!ok);
  if (bad == 0ull) return;
  __shared__ float rv[128];
  __shared__ float lst[64][10];
  const __bf16* an = an_all + (size_t)dir * NB * ND;
  while (bad) {
    int b = __ffsll((long long)bad) - 1;
    bad &= bad - 1;
    int brow = (blockIdx.x * 64 + b) & (NB - 1);
    bf16x2 pr = ((const bf16x2*)an)[(size_t)brow * 64 + lane];
    rv[lane * 2] = (float)pr[0];
    rv[lane * 2 + 1] = (float)pr[1];
    __syncthreads();
    float t10[10];
#pragma unroll
    for (int j = 0; j < 10; ++j) t10[j] = NEG_INF;
    for (int i = 0; i < 128; ++i) {
      int col = lane + i * 64;
      if (col == brow) continue;
      const bf16x8* cp = (const bf16x8*)(an + (size_t)col * ND);
      float d = 0.f;
#pragma unroll
      for (int k = 0; k < 16; ++k) {
        bf16x8 p = cp[k];
#pragma unroll
        for (int e = 0; e < 8; ++e) d = fmaf(rv[k * 8 + e], (float)p[e], d);
      }
      if (d > t10[0]) insert10(t10, d);
    }
#pragma unroll
    for (int j = 0; j < 10; ++j) lst[lane][j] = t10[j];
    __syncthreads();
    if (lane == 0) {
      float cur[10];
#pragma unroll
      for (int j = 0; j < 10; ++j) cur[j] = lst[0][j];
      for (int s = 1; s < 64; ++s)
        for (int j = 0; j < 10; ++j) {
          float v = lst[s][j];
          if (v > cur[0]) insert10(cur, v);
        }
      float x[11];
#pragma unroll
      for (int j = 0; j < 10; ++j) x[j] = cur[j];
      x[10] = pos[brow];
      atomicAdd(out, row_loss(x) * (-1.f / (2.f * (float)NB * 11.f)));
    }
    __syncthreads();
  }
}

// ---------------------------------------------------------------------------
// ws: [an bf16 4MB][pos 32KB][tk 1.31MB][cnth 128KB][taug 2KB]. 3 nodes, no
// memsets: knorm zeroes d_out; cnth/taug written unconditionally by kgram.
// ---------------------------------------------------------------------------
extern "C" void kernel_launch(void* const* d_in, const int* in_sizes, int n_in,
                              void* d_out, int out_size, void* d_ws, size_t ws_size,
                              hipStream_t stream) {
  const float* aug1 = (const float*)d_in[0];
  const float* aug2 = (const float*)d_in[1];
  char* w = (char*)d_ws;
  __bf16* an = (__bf16*)w;
  float* pos = (float*)(w + (size_t)4 * 1024 * 1024);
  float* tk = pos + NB;
  int* cnth = (int*)(tk + (size_t)2 * NB * 20);
  float* taug = (float*)(cnth + 2 * NB * 2);

  knorm<<<dim3(NB / 4), dim3(256), 0, stream>>>(aug1, aug2, an, pos, (float*)d_out);
  kgram<<<dim3(256, 2), dim3(256), 0, stream>>>(an, tk, cnth, taug);
  ksort<<<dim3(2 * NB / 64), dim3(64), 0, stream>>>(tk, pos, cnth, taug, an, (float*)d_out);
}

// Round 4
// 148.836 us; speedup vs baseline: 8.1410x; 1.0586x over previous
//
#include <hip/hip_runtime.h>
#include <cstdint>
#include <cmath>

#define NB 8192
#define ND 128
#define CAP 48
#define CAPP 49  // odd stride: epilogue bank = (rl*49+i)%32, 2 lanes/bank = free
#define NEG_INF (-__builtin_inff())

typedef __attribute__((ext_vector_type(8))) __bf16 bf16x8;
typedef __attribute__((ext_vector_type(2))) __bf16 bf16x2;
typedef __attribute__((ext_vector_type(4))) float f32x4;

// Insert v into ascending top-K list (identity when v <= t[0]).
__device__ __forceinline__ void insert10(float t[10], float v) {
#pragma unroll
  for (int j = 0; j < 9; ++j) t[j] = __builtin_amdgcn_fmed3f(t[j], t[j + 1], v);
  t[9] = fmaxf(t[9], v);
}
__device__ __forceinline__ void insert11(float t[11], float v) {
#pragma unroll
  for (int j = 0; j < 10; ++j) t[j] = __builtin_amdgcn_fmed3f(t[j], t[j + 1], v);
  t[10] = fmaxf(t[10], v);
}

// ---------------------------------------------------------------------------
// Row loss via column-10-only soft sort (P row-stochastic => p_neg = 1-p_pos,
// clips no-ops, both BCEs identical). Verified exact (absmax 0.0).
// ---------------------------------------------------------------------------
__device__ float row_loss(float x[11]) {
  float al[55];
#pragma unroll
  for (int layer = 0; layer < 11; ++layer) {
#pragma unroll
    for (int p = 0; p < 5; ++p) {
      int ii = (layer & 1) + 2 * p;
      float av = x[ii], bv = x[ii + 1];
      float a = atanf(bv - av) * 0.3183098861837907f + 0.5f;
      al[layer * 5 + p] = a;
      float be = 1.f - a;
      x[ii] = a * av + be * bv;
      x[ii + 1] = be * av + a * bv;
    }
  }
  float v[11];
#pragma unroll
  for (int i = 0; i < 11; ++i) v[i] = 0.f;
  v[10] = 1.f;
#pragma unroll
  for (int layer = 10; layer >= 0; --layer) {
#pragma unroll
    for (int p = 0; p < 5; ++p) {
      int ii = (layer & 1) + 2 * p;
      float a = al[layer * 5 + p];
      float be = 1.f - a;
      float va = v[ii], vb = v[ii + 1];
      v[ii] = a * va + be * vb;
      v[ii + 1] = be * va + a * vb;
    }
  }
  float C = fmaxf(logf(v[10]), -100.f);
#pragma unroll
  for (int i = 0; i < 10; ++i) C += fmaxf(logf(1.f - v[i]), -100.f);
  return C;
}

// ---------------------------------------------------------------------------
// Kernel 1: row-normalize -> bf16 + fp32 pos_sims. Block 0 zeroes d_out.
// ---------------------------------------------------------------------------
__global__ __launch_bounds__(256, 4) void knorm(const float* __restrict__ aug1,
                                                const float* __restrict__ aug2,
                                                __bf16* __restrict__ an,
                                                float* __restrict__ pos,
                                                float* __restrict__ out) {
  if (blockIdx.x == 0 && threadIdx.x == 0) out[0] = 0.f;
  int wid = threadIdx.x >> 6;
  int l = threadIdx.x & 63;
  int row = blockIdx.x * 4 + wid;
  const float2* a1 = (const float2*)(aug1) + (size_t)row * 64;
  const float2* a2 = (const float2*)(aug2) + (size_t)row * 64;
  float2 v1 = a1[l], v2 = a2[l];
  float ss1 = v1.x * v1.x + v1.y * v1.y;
  float ss2 = v2.x * v2.x + v2.y * v2.y;
  float dp = v1.x * v2.x + v1.y * v2.y;
#pragma unroll
  for (int off = 1; off < 64; off <<= 1) {
    ss1 += __shfl_xor(ss1, off);
    ss2 += __shfl_xor(ss2, off);
    dp += __shfl_xor(dp, off);
  }
  float inv1 = 1.0f / fmaxf(sqrtf(ss1), 1e-8f);
  float inv2 = 1.0f / fmaxf(sqrtf(ss2), 1e-8f);
  bf16x2 o1, o2;
  o1[0] = (__bf16)(v1.x * inv1);
  o1[1] = (__bf16)(v1.y * inv1);
  o2[0] = (__bf16)(v2.x * inv2);
  o2[1] = (__bf16)(v2.y * inv2);
  ((bf16x2*)(an))[(size_t)row * 64 + l] = o1;
  ((bf16x2*)(an + (size_t)NB * ND))[(size_t)row * 64 + l] = o2;
  if (l == 0) pos[row] = dp * inv1 * inv2;
}

// ---------------------------------------------------------------------------
// Kernel 2: fused Gram + threshold filter, rebuilt for arithmetic intensity.
// R0-R3 diagnosis: per-CU vmem streaming BW (~11 B/cy) was saturated at
// 64-row reuse (2.1 MB/CU); waves (R1), prefetch depth (R2), LDS 2-phase at
// same traffic (R3) all flat -> BW-bound. This version: 256 rows/block
// (8 waves x 64 rows in registers), 2048-col quarter streamed as 32 x 64-col
// LDS tiles SHARED by all waves -> 0.59 MB/CU (3.6x less traffic).
// LDS tile XOR-swizzled both sides (rule #21): linear DMA dest; source unit
// pre-XORed with (col&7); ds_read XORs identically. MFMA operand mapping
// byte-identical to R0's verified kernel => absmax 0.0.
// Diagonal: self-sim (=1.0 > tau) enters cand; epilogue drops per-row max
// in the diag-overlapping quarter. Counts/taus written unconditionally.
// ---------------------------------------------------------------------------
__global__ __launch_bounds__(512, 1) void kgram(const __bf16* __restrict__ an_all,
                                                float* __restrict__ tk,
                                                int* __restrict__ cnth,
                                                float* __restrict__ taug) {
  int dir = blockIdx.y;
  int rowg = blockIdx.x >> 2;  // 0..31 (256-row groups)
  int quar = blockIdx.x & 3;   // 0..3  (2048-col quarters)
  const __bf16* an = an_all + (size_t)dir * NB * ND;
  const bf16x8* an8 = (const bf16x8*)an;
  int w = threadIdx.x >> 6;  // 0..7
  int l = threadIdx.x & 63;
  int q = l >> 4;
  int c = l & 15;
  int wr = w >> 1;  // wave row-group 0..3 (64 rows each)
  int wc = w & 1;   // wave col-half 0..1 (32 cols of each 64-col tile)
  int row_base = rowg * 256;
  const int col0 = quar * 2048;

  __shared__ char sbuf[2][16384];    // double-buffered 64col x 256B tile
  __shared__ float cand[256][CAPP];  // survivor values per block-row
  __shared__ int lcnt[256];
  __shared__ float sred[2][8];
  if (threadIdx.x < 256) lcnt[threadIdx.x] = 0;

  // Row fragments (B-operand), resident all kernel: rows wr*64 + rb*16 + c.
  bf16x8 brow[4][4];
#pragma unroll
  for (int rb = 0; rb < 4; ++rb)
#pragma unroll
    for (int kc = 0; kc < 4; ++kc)
      brow[rb][kc] =
          an8[(size_t)(row_base + wr * 64 + rb * 16 + c) * 16 + kc * 4 + q];

  // ---- staging: tile t = 16KB contiguous at panel + t*16384. Wave w DMAs
  // bytes [w*2048, w*2048+2048) linearly (2 x 1KB gload_lds); lane l lands at
  // local col = w*8 + k*4 + q, unit c. Source unit pre-swizzled: c^(k*4+q)
  // (= c ^ (col&7)), so LDS[col][u] = G[col][u ^ (col&7)].
  const char* panel = (const char*)an + (size_t)col0 * 256;
  const int s0 = (w * 8 + 0 + q) * 256 + ((c ^ (0 + q)) << 4);
  const int s1 = (w * 8 + 4 + q) * 256 + ((c ^ (4 + q)) << 4);
  auto stage = [&](int buf, int t) {
    const char* tb = panel + (size_t)t * 16384;
    char* db = &sbuf[buf][w * 2048];  // wave-uniform dest; HW adds lane*16
    __builtin_amdgcn_global_load_lds(
        (const __attribute__((address_space(1))) void*)(tb + s0),
        (__attribute__((address_space(3))) void*)(db), 16, 0, 0);
    __builtin_amdgcn_global_load_lds(
        (const __attribute__((address_space(1))) void*)(tb + s1),
        (__attribute__((address_space(3))) void*)(db + 1024), 16, 0, 0);
  };

  // ---- fragment reads: want G[rcol][kc*4+q] for rcol = wc*32 + n*16 + c;
  // read u = (kc*4+q) ^ (rcol&7) = (kc*4+q) ^ (c&7). Per 8-lane group the
  // bank index (u&7) is a bijection of c&7 -> conflict-free.
  int rdo[2][4];
#pragma unroll
  for (int n = 0; n < 2; ++n)
#pragma unroll
    for (int kc = 0; kc < 4; ++kc)
      rdo[n][kc] = (wc * 32 + n * 16 + c) * 256 +
                   (((kc * 4 + q) ^ (c & 7)) << 4);

  const f32x4 zz = {0.f, 0.f, 0.f, 0.f};
  bf16x8 afr[2][4];
  f32x4 acc[2][4];  // [n][rb]
  auto compute_tile = [&](int buf) {
    const char* bp = &sbuf[buf][0];
#pragma unroll
    for (int n = 0; n < 2; ++n)
#pragma unroll
      for (int kc = 0; kc < 4; ++kc)
        afr[n][kc] = *(const bf16x8*)(bp + rdo[n][kc]);
#pragma unroll
    for (int n = 0; n < 2; ++n)
#pragma unroll
      for (int rb = 0; rb < 4; ++rb)
        acc[n][rb] = __builtin_amdgcn_mfma_f32_16x16x32_bf16(
            afr[n][0], brow[rb][0], zz, 0, 0, 0);
#pragma unroll
    for (int kc = 1; kc < 4; ++kc)
#pragma unroll
      for (int n = 0; n < 2; ++n)
#pragma unroll
        for (int rb = 0; rb < 4; ++rb)
          acc[n][rb] = __builtin_amdgcn_mfma_f32_16x16x32_bf16(
              afr[n][kc], brow[rb][kc], acc[n][rb], 0, 0, 0);
  };

  float tau;  // set after tile-0 stats
  auto consume = [&]() {
#pragma unroll
    for (int n = 0; n < 2; ++n)
#pragma unroll
      for (int rb = 0; rb < 4; ++rb) {
        int rl = wr * 64 + rb * 16 + c;
#pragma unroll
        for (int r = 0; r < 4; ++r) {
          float v = acc[n][rb][r];
          if (v > tau) {
            int s = atomicAdd(&lcnt[rl], 1);
            if (s < CAP) cand[rl][s] = v;
          }
        }
      }
  };

  // ---- prologue: tile 0 compute + stats (diag-masked) + tau ----
  stage(0, 0);
  __syncthreads();  // vmcnt(0)+barrier: t0 staged, lcnt zeroed
  stage(1, 1);      // prefetch t1; drained by the stats barrier below
  compute_tile(0);
  bool diag0 = (row_base == col0);  // tile-0 holds diag cells iff equal
  float s1v = 0.f, s2v = 0.f;
#pragma unroll
  for (int n = 0; n < 2; ++n)
#pragma unroll
    for (int rb = 0; rb < 4; ++rb) {
      int grow = row_base + wr * 64 + rb * 16 + c;
      int gcolb = col0 + wc * 32 + n * 16 + q * 4;
#pragma unroll
      for (int r = 0; r < 4; ++r) {
        float v = acc[n][rb][r];
        v = (diag0 && (gcolb + r == grow)) ? 0.f : v;
        s1v += v;
        s2v = fmaf(v, v, s2v);
      }
    }
#pragma unroll
  for (int off = 1; off < 64; off <<= 1) {
    s1v += __shfl_xor(s1v, off);
    s2v += __shfl_xor(s2v, off);
  }
  if (l == 0) { sred[0][w] = s1v; sred[1][w] = s2v; }
  __syncthreads();  // sred ready; stage(t1) drained
  float nn = diag0 ? 16320.f : 16384.f;
  float ts1 = 0.f, ts2 = 0.f;
#pragma unroll
  for (int i = 0; i < 8; ++i) { ts1 += sred[0][i]; ts2 += sred[1][i]; }
  float mu = ts1 / nn;
  float sig = sqrtf(fmaxf(ts2 / nn - mu * mu, 0.f));
  tau = mu + 2.5f * sig;  // lambda ~12.7 survivors per row-quarter
  if (threadIdx.x == 0) taug[((size_t)dir * 32 + rowg) * 4 + quar] = tau;
  consume();  // t0

  // ---- steady state: tiles 1..31, 2-phase double-buffer, stage-early ----
  for (int t = 1; t < 32; ++t) {
    int cur = t & 1;
    if (t < 31) stage(cur ^ 1, t + 1);  // overwrites t-1's buffer (its reads
                                        // completed before previous barrier)
    compute_tile(cur);
    consume();
    __syncthreads();  // drains stage(t+1) + this tile's LDS ops
  }

  // ---- epilogue: per-row top-11; drop max if quarter contains the diag ----
  if (threadIdx.x < 256) {
    int rl = threadIdx.x;
    int cc = lcnt[rl];
    float t11[11];
#pragma unroll
    for (int j = 0; j < 11; ++j) t11[j] = NEG_INF;
    int m = cc < CAP ? cc : CAP;
    for (int i = 0; i < m; ++i) {
      float v = cand[rl][i];
      if (v > t11[0]) insert11(t11, v);
    }
    bool diagq = ((rowg >> 3) == quar);  // rows of this block lie in quarter
    int row = row_base + rl;
    float* o = tk + ((size_t)(dir * NB + row) * 4 + quar) * 10;
    if (diagq) {  // t11[10] is the self-sim (max) -> drop it
#pragma unroll
      for (int j = 0; j < 10; ++j) o[j] = t11[j];
    } else {  // keep the 10 largest
#pragma unroll
      for (int j = 0; j < 10; ++j) o[j] = t11[j + 1];
    }
    cnth[(size_t)(dir * NB + row) * 4 + quar] = cc;
  }
}

// ---------------------------------------------------------------------------
// Kernel 3: merge quarter-lists, tau-proof, soft-sort + BCE; exact brute-
// force fallback for unproven rows (statistically never fires).
// ---------------------------------------------------------------------------
__global__ __launch_bounds__(64, 1) void ksort(const float* __restrict__ tk,
                                               const float* __restrict__ pos,
                                               const int* __restrict__ cnth,
                                               const float* __restrict__ taug,
                                               const __bf16* __restrict__ an_all,
                                               float* __restrict__ out) {
  int tid = blockIdx.x * 64 + threadIdx.x;
  int dir = tid >> 13;
  int row = tid & (NB - 1);
  int lane = threadIdx.x;

  const float* A = tk + (size_t)(dir * NB + row) * 40;
  float s10[10];
#pragma unroll
  for (int j = 0; j < 10; ++j) s10[j] = A[j];
#pragma unroll
  for (int h = 1; h < 4; ++h) {
#pragma unroll
    for (int j = 0; j < 10; ++j) {
      float v = A[h * 10 + j];
      if (v > s10[0]) insert10(s10, v);
    }
  }
  int rowg = row >> 8;
  const float* tg = taug + ((size_t)dir * 32 + rowg) * 4;
  float tmax = fmaxf(fmaxf(tg[0], tg[1]), fmaxf(tg[2], tg[3]));
  int4 cc4 = ((const int4*)cnth)[dir * NB + row];
  // Proof: every unreported sim is <= its quarter's tau <= tmax <= s10[0],
  // and no quarter overflowed CAP -> s10 is the exact top-10.
  bool ok = (cc4.x <= CAP) && (cc4.y <= CAP) && (cc4.z <= CAP) &&
            (cc4.w <= CAP) && (s10[0] >= tmax);

  float C = 0.f;
  if (ok) {
    float x[11];
#pragma unroll
    for (int j = 0; j < 10; ++j) x[j] = s10[j];
    x[10] = pos[row];
    C = row_loss(x);
  }
#pragma unroll
  for (int off = 1; off < 64; off <<= 1) C += __shfl_xor(C, off);
  if (lane == 0) atomicAdd(out, C * (-1.f / (2.f * (float)NB * 11.f)));

  unsigned long long bad = __ballot(!ok);
  if (bad == 0ull) return;
  __shared__ float rv[128];
  __shared__ float lst[64][10];
  const __bf16* an = an_all + (size_t)dir * NB * ND;
  while (bad) {
    int b = __ffsll((long long)bad) - 1;
    bad &= bad - 1;
    int brow = (blockIdx.x * 64 + b) & (NB - 1);
    bf16x2 pr = ((const bf16x2*)an)[(size_t)brow * 64 + lane];
    rv[lane * 2] = (float)pr[0];
    rv[lane * 2 + 1] = (float)pr[1];
    __syncthreads();
    float t10[10];
#pragma unroll
    for (int j = 0; j < 10; ++j) t10[j] = NEG_INF;
    for (int i = 0; i < 128; ++i) {
      int col = lane + i * 64;
      if (col == brow) continue;
      const bf16x8* cp = (const bf16x8*)(an + (size_t)col * ND);
      float d = 0.f;
#pragma unroll
      for (int k = 0; k < 16; ++k) {
        bf16x8 p = cp[k];
#pragma unroll
        for (int e = 0; e < 8; ++e) d = fmaf(rv[k * 8 + e], (float)p[e], d);
      }
      if (d > t10[0]) insert10(t10, d);
    }
#pragma unroll
    for (int j = 0; j < 10; ++j) lst[lane][j] = t10[j];
    __syncthreads();
    if (lane == 0) {
      float cur[10];
#pragma unroll
      for (int j = 0; j < 10; ++j) cur[j] = lst[0][j];
      for (int s = 1; s < 64; ++s)
        for (int j = 0; j < 10; ++j) {
          float v = lst[s][j];
          if (v > cur[0]) insert10(cur, v);
        }
      float x[11];
#pragma unroll
      for (int j = 0; j < 10; ++j) x[j] = cur[j];
      x[10] = pos[brow];
      atomicAdd(out, row_loss(x) * (-1.f / (2.f * (float)NB * 11.f)));
    }
    __syncthreads();
  }
}

// ---------------------------------------------------------------------------
// ws: [an bf16 4MB][pos 32KB][tk 2.62MB][cnth 256KB][taug 1KB] ~= 7.0 MB.
// 3 nodes, no memsets: knorm zeroes d_out; cnth/taug written unconditionally.
// ---------------------------------------------------------------------------
extern "C" void kernel_launch(void* const* d_in, const int* in_sizes, int n_in,
                              void* d_out, int out_size, void* d_ws, size_t ws_size,
                              hipStream_t stream) {
  const float* aug1 = (const float*)d_in[0];
  const float* aug2 = (const float*)d_in[1];
  char* w = (char*)d_ws;
  __bf16* an = (__bf16*)w;
  float* pos = (float*)(w + (size_t)4 * 1024 * 1024);
  float* tk = pos + NB;
  int* cnth = (int*)(tk + (size_t)2 * NB * 40);
  float* taug = (float*)(cnth + (size_t)2 * NB * 4);

  knorm<<<dim3(NB / 4), dim3(256), 0, stream>>>(aug1, aug2, an, pos, (float*)d_out);
  kgram<<<dim3(128, 2), dim3(512), 0, stream>>>(an, tk, cnth, taug);
  ksort<<<dim3(2 * NB / 64), dim3(64), 0, stream>>>(tk, pos, cnth, taug, an, (float*)d_out);
}

// Round 5
// 146.001 us; speedup vs baseline: 8.2991x; 1.0194x over previous
//
#include <hip/hip_runtime.h>
#include <cstdint>
#include <cmath>

#define NB 8192
#define ND 128
#define CAP 48
#define CAPP 49  // odd stride: epilogue bank = (rl*49+i)%32 bijective -> free
#define NEG_INF (-__builtin_inff())

typedef __attribute__((ext_vector_type(8))) __bf16 bf16x8;
typedef __attribute__((ext_vector_type(2))) __bf16 bf16x2;
typedef __attribute__((ext_vector_type(4))) float f32x4;
typedef __attribute__((ext_vector_type(16))) float f32x16;

// Insert v into ascending top-K list (identity when v <= t[0]).
__device__ __forceinline__ void insert10(float t[10], float v) {
#pragma unroll
  for (int j = 0; j < 9; ++j) t[j] = __builtin_amdgcn_fmed3f(t[j], t[j + 1], v);
  t[9] = fmaxf(t[9], v);
}
__device__ __forceinline__ void insert11(float t[11], float v) {
#pragma unroll
  for (int j = 0; j < 10; ++j) t[j] = __builtin_amdgcn_fmed3f(t[j], t[j + 1], v);
  t[10] = fmaxf(t[10], v);
}

// ---------------------------------------------------------------------------
// Row loss via column-10-only soft sort (P row-stochastic => p_neg = 1-p_pos,
// clips no-ops, both BCEs identical). Verified exact (absmax 0.0).
// ---------------------------------------------------------------------------
__device__ float row_loss(float x[11]) {
  float al[55];
#pragma unroll
  for (int layer = 0; layer < 11; ++layer) {
#pragma unroll
    for (int p = 0; p < 5; ++p) {
      int ii = (layer & 1) + 2 * p;
      float av = x[ii], bv = x[ii + 1];
      float a = atanf(bv - av) * 0.3183098861837907f + 0.5f;
      al[layer * 5 + p] = a;
      float be = 1.f - a;
      x[ii] = a * av + be * bv;
      x[ii + 1] = be * av + a * bv;
    }
  }
  float v[11];
#pragma unroll
  for (int i = 0; i < 11; ++i) v[i] = 0.f;
  v[10] = 1.f;
#pragma unroll
  for (int layer = 10; layer >= 0; --layer) {
#pragma unroll
    for (int p = 0; p < 5; ++p) {
      int ii = (layer & 1) + 2 * p;
      float a = al[layer * 5 + p];
      float be = 1.f - a;
      float va = v[ii], vb = v[ii + 1];
      v[ii] = a * va + be * vb;
      v[ii + 1] = be * va + a * vb;
    }
  }
  float C = fmaxf(logf(v[10]), -100.f);
#pragma unroll
  for (int i = 0; i < 10; ++i) C += fmaxf(logf(1.f - v[i]), -100.f);
  return C;
}

// ---------------------------------------------------------------------------
// Kernel 1: row-normalize -> bf16 + fp32 pos_sims. Block 0 zeroes d_out.
// ---------------------------------------------------------------------------
__global__ __launch_bounds__(256, 4) void knorm(const float* __restrict__ aug1,
                                                const float* __restrict__ aug2,
                                                __bf16* __restrict__ an,
                                                float* __restrict__ pos,
                                                float* __restrict__ out) {
  if (blockIdx.x == 0 && threadIdx.x == 0) out[0] = 0.f;
  int wid = threadIdx.x >> 6;
  int l = threadIdx.x & 63;
  int row = blockIdx.x * 4 + wid;
  const float2* a1 = (const float2*)(aug1) + (size_t)row * 64;
  const float2* a2 = (const float2*)(aug2) + (size_t)row * 64;
  float2 v1 = a1[l], v2 = a2[l];
  float ss1 = v1.x * v1.x + v1.y * v1.y;
  float ss2 = v2.x * v2.x + v2.y * v2.y;
  float dp = v1.x * v2.x + v1.y * v2.y;
#pragma unroll
  for (int off = 1; off < 64; off <<= 1) {
    ss1 += __shfl_xor(ss1, off);
    ss2 += __shfl_xor(ss2, off);
    dp += __shfl_xor(dp, off);
  }
  float inv1 = 1.0f / fmaxf(sqrtf(ss1), 1e-8f);
  float inv2 = 1.0f / fmaxf(sqrtf(ss2), 1e-8f);
  bf16x2 o1, o2;
  o1[0] = (__bf16)(v1.x * inv1);
  o1[1] = (__bf16)(v1.y * inv1);
  o2[0] = (__bf16)(v2.x * inv2);
  o2[1] = (__bf16)(v2.y * inv2);
  ((bf16x2*)(an))[(size_t)row * 64 + l] = o1;
  ((bf16x2*)(an + (size_t)NB * ND))[(size_t)row * 64 + l] = o2;
  if (l == 0) pos[row] = dp * inv1 * inv2;
}

// ---------------------------------------------------------------------------
// Kernel 2: fused Gram + threshold filter. R0-R4 showed time invariant
// (74-92us, MfmaUtil ~16%) under occupancy, prefetch depth, staging mode and
// 3.6x traffic changes -> bottleneck = per-wave instruction-stream overhead.
// This version: 32x32x16 MFMA (half the MFMA/ds_read instructions per FLOP,
// C/D layout per guide m74/m101: col=lane&31, row=(reg&3)+8*(reg>>2)+
// 4*(lane>>5); operands symmetric: row=lane&31, k=(lane>>5)*8+e), zero
// per-tile address VALU (precomputed uoff[8], literal buf offsets), setprio
// around MFMA cluster. Block: 128 rows x 2048-col quarter, 4 waves (wave =
// 32 rows x 64 cols/tile), 2 blocks/CU. LDS staging with the R4-verified
// both-sides XOR swizzle (LDS[col][u] = G[col][u^(col&7)]); read pattern is
// 4-lane same-address broadcast + 2 lanes/bank = conflict-free.
// Diagonal: self-sim (=1.0 > tau) enters cand; epilogue drops per-row max
// in the diag-overlapping quarter. Counts/taus written unconditionally.
// ---------------------------------------------------------------------------
__global__ __launch_bounds__(256, 2) void kgram(const __bf16* __restrict__ an_all,
                                                float* __restrict__ tk,
                                                int* __restrict__ cnth,
                                                float* __restrict__ taug) {
  int dir = blockIdx.y;
  int rowg = blockIdx.x >> 2;  // 0..63 (128-row groups)
  int quar = blockIdx.x & 3;   // 0..3  (2048-col quarters)
  const __bf16* an = an_all + (size_t)dir * NB * ND;
  const bf16x8* an8 = (const bf16x8*)an;
  int w = threadIdx.x >> 6;  // 0..3
  int l = threadIdx.x & 63;
  int cl = l & 31;  // MFMA row/col lane index
  int h = l >> 5;   // k-half
  int q = l >> 4;   // staging sub-indices (R4 pattern)
  int c = l & 15;
  int row_base = rowg * 128;
  const int col0 = quar * 2048;

  __shared__ char sbuf[2][16384];    // double-buffered 64col x 256B tile
  __shared__ float cand[128][CAPP];  // survivor values per block-row
  __shared__ int lcnt[128];
  __shared__ float sred[2][4];
  if (threadIdx.x < 128) lcnt[threadIdx.x] = 0;

  // Row fragments (B-operand), resident all kernel: row = row_base+w*32+cl,
  // k = h*8+e within each K=16 step; 8 steps cover K=128.
  int grow = row_base + w * 32 + cl;
  bf16x8 brow[8];
#pragma unroll
  for (int ks = 0; ks < 8; ++ks)
    brow[ks] = an8[(size_t)grow * 16 + ks * 2 + h];

  // ---- staging (R4-verified swizzle): wave w DMAs cols w*16..w*16+15.
  // Lane l -> dest col = w*16 + k*4 + (l>>4), unit l&15; source unit
  // pre-XORed with col&7 = (k&1)*4 + q, so LDS[col][u] = G[col][u^(col&7)].
  const char* panel = (const char*)an + (size_t)col0 * 256;
  const int sE = (w * 16 + q) * 256 + ((c ^ q) << 4);           // k even
  const int sO = (w * 16 + q) * 256 + (((c ^ q) ^ 4) << 4);     // k odd
  auto stage = [&](int buf, int t) {
    const char* tb = panel + (size_t)t * 16384;
    char* db = &sbuf[buf][w * 4096];  // wave-uniform dest; HW adds lane*16
#pragma unroll
    for (int k = 0; k < 4; ++k) {
      const char* src = tb + ((k & 1) ? sO : sE) + k * 1024;
      __builtin_amdgcn_global_load_lds(
          (const __attribute__((address_space(1))) void*)src,
          (__attribute__((address_space(3))) void*)(db + k * 1024), 16, 0, 0);
    }
  };

  // ---- fragment read offsets (per ks), computed ONCE: A-operand for staged
  // col = cg*32 + cl, unit u = ks*2 + h, swizzled u ^= (col&7) = (cl&7).
  int uoff[8];
#pragma unroll
  for (int ks = 0; ks < 8; ++ks) uoff[ks] = ((ks * 2 + h) ^ (cl & 7)) << 4;
  const int cb = cl * 256;

  f32x16 acc0, acc1;
  auto compute_tile = [&](int buf) {
    const char* bp = &sbuf[0][0] + buf * 16384;
#pragma unroll
    for (int e = 0; e < 16; ++e) { acc0[e] = 0.f; acc1[e] = 0.f; }
    __builtin_amdgcn_s_setprio(1);
#pragma unroll
    for (int ks = 0; ks < 8; ++ks) {
      bf16x8 fa = *(const bf16x8*)(bp + cb + uoff[ks]);
      bf16x8 fb = *(const bf16x8*)(bp + 8192 + cb + uoff[ks]);
      acc0 = __builtin_amdgcn_mfma_f32_32x32x16_bf16(fa, brow[ks], acc0, 0, 0, 0);
      acc1 = __builtin_amdgcn_mfma_f32_32x32x16_bf16(fb, brow[ks], acc1, 0, 0, 0);
    }
    __builtin_amdgcn_s_setprio(0);
  };

  float tau;  // set after tile-0 stats
  int rl = w * 32 + cl;
  auto consume = [&]() {
#pragma unroll
    for (int e = 0; e < 16; ++e) {
      float v = acc0[e];
      if (v > tau) {
        int s = atomicAdd(&lcnt[rl], 1);
        if (s < CAP) cand[rl][s] = v;
      }
    }
#pragma unroll
    for (int e = 0; e < 16; ++e) {
      float v = acc1[e];
      if (v > tau) {
        int s = atomicAdd(&lcnt[rl], 1);
        if (s < CAP) cand[rl][s] = v;
      }
    }
  };

  // ---- prologue: tile 0 compute + stats (diag-masked) + tau ----
  stage(0, 0);
  __syncthreads();  // vmcnt(0)+barrier: t0 staged, lcnt zeroed
  stage(1, 1);      // prefetch t1; drained by the stats barrier below
  compute_tile(0);
  bool diag0 = (row_base == col0);  // only alignment putting diag in tile 0
  float s1v = 0.f, s2v = 0.f;
#pragma unroll
  for (int cg = 0; cg < 2; ++cg) {
#pragma unroll
    for (int e = 0; e < 16; ++e) {
      int gcol = col0 + cg * 32 + (e & 3) + 8 * (e >> 2) + 4 * h;
      float v = cg ? acc1[e] : acc0[e];
      v = (diag0 && (gcol == grow)) ? 0.f : v;
      s1v += v;
      s2v = fmaf(v, v, s2v);
    }
  }
#pragma unroll
  for (int off = 1; off < 64; off <<= 1) {
    s1v += __shfl_xor(s1v, off);
    s2v += __shfl_xor(s2v, off);
  }
  if (l == 0) { sred[0][w] = s1v; sred[1][w] = s2v; }
  __syncthreads();  // sred ready; stage(t1) drained
  float nn = diag0 ? 8128.f : 8192.f;  // 128x64 cells, 64 diag-masked
  float ts1 = sred[0][0] + sred[0][1] + sred[0][2] + sred[0][3];
  float ts2 = sred[1][0] + sred[1][1] + sred[1][2] + sred[1][3];
  float mu = ts1 / nn;
  float sig = sqrtf(fmaxf(ts2 / nn - mu * mu, 0.f));
  tau = mu + 2.5f * sig;  // lambda ~12.7 survivors per row-quarter
  if (threadIdx.x == 0) taug[((size_t)dir * 64 + rowg) * 4 + quar] = tau;
  consume();  // t0

  // ---- steady state: tiles 1..31, 2-phase, literal buffer indices ----
  for (int t = 1; t < 32; t += 2) {
    // tile t (odd) in buf1; prefetch t+1 -> buf0 (overwrites t-1, whose
    // reads completed before the previous barrier).
    if (t + 1 < 32) stage(0, t + 1);
    compute_tile(1);
    consume();
    __syncthreads();
    if (t + 1 < 32) {
      if (t + 2 < 32) stage(1, t + 2);
      compute_tile(0);
      consume();
      __syncthreads();
    }
  }

  // ---- epilogue: per-row top-11; drop max if quarter contains the diag ----
  if (threadIdx.x < 128) {
    int r = threadIdx.x;
    int cc = lcnt[r];
    float t11[11];
#pragma unroll
    for (int j = 0; j < 11; ++j) t11[j] = NEG_INF;
    int m = cc < CAP ? cc : CAP;
    for (int i = 0; i < m; ++i) {
      float v = cand[r][i];
      if (v > t11[0]) insert11(t11, v);
    }
    bool diagq = ((rowg >> 4) == quar);  // block rows' diag lies in quarter
    int row = row_base + r;
    float* o = tk + ((size_t)(dir * NB + row) * 4 + quar) * 10;
    if (diagq) {  // t11[10] is the self-sim (max) -> drop it
#pragma unroll
      for (int j = 0; j < 10; ++j) o[j] = t11[j];
    } else {  // keep the 10 largest
#pragma unroll
      for (int j = 0; j < 10; ++j) o[j] = t11[j + 1];
    }
    cnth[(size_t)(dir * NB + row) * 4 + quar] = cc;
  }
}

// ---------------------------------------------------------------------------
// Kernel 3: merge quarter-lists, tau-proof, soft-sort + BCE; exact brute-
// force fallback for unproven rows (statistically never fires).
// ---------------------------------------------------------------------------
__global__ __launch_bounds__(64, 1) void ksort(const float* __restrict__ tk,
                                               const float* __restrict__ pos,
                                               const int* __restrict__ cnth,
                                               const float* __restrict__ taug,
                                               const __bf16* __restrict__ an_all,
                                               float* __restrict__ out) {
  int tid = blockIdx.x * 64 + threadIdx.x;
  int dir = tid >> 13;
  int row = tid & (NB - 1);
  int lane = threadIdx.x;

  const float* A = tk + (size_t)(dir * NB + row) * 40;
  float s10[10];
#pragma unroll
  for (int j = 0; j < 10; ++j) s10[j] = A[j];
#pragma unroll
  for (int h = 1; h < 4; ++h) {
#pragma unroll
    for (int j = 0; j < 10; ++j) {
      float v = A[h * 10 + j];
      if (v > s10[0]) insert10(s10, v);
    }
  }
  int rowg = row >> 7;
  const float* tg = taug + ((size_t)dir * 64 + rowg) * 4;
  float tmax = fmaxf(fmaxf(tg[0], tg[1]), fmaxf(tg[2], tg[3]));
  int4 cc4 = ((const int4*)cnth)[dir * NB + row];
  // Proof: every unreported sim is <= its quarter's tau <= tmax <= s10[0],
  // and no quarter overflowed CAP -> s10 is the exact top-10.
  bool ok = (cc4.x <= CAP) && (cc4.y <= CAP) && (cc4.z <= CAP) &&
            (cc4.w <= CAP) && (s10[0] >= tmax);

  float C = 0.f;
  if (ok) {
    float x[11];
#pragma unroll
    for (int j = 0; j < 10; ++j) x[j] = s10[j];
    x[10] = pos[row];
    C = row_loss(x);
  }
#pragma unroll
  for (int off = 1; off < 64; off <<= 1) C += __shfl_xor(C, off);
  if (lane == 0) atomicAdd(out, C * (-1.f / (2.f * (float)NB * 11.f)));

  unsigned long long bad = __ballot(!ok);
  if (bad == 0ull) return;
  __shared__ float rv[128];
  __shared__ float lst[64][10];
  const __bf16* an = an_all + (size_t)dir * NB * ND;
  while (bad) {
    int b = __ffsll((long long)bad) - 1;
    bad &= bad - 1;
    int brow = (blockIdx.x * 64 + b) & (NB - 1);
    bf16x2 pr = ((const bf16x2*)an)[(size_t)brow * 64 + lane];
    rv[lane * 2] = (float)pr[0];
    rv[lane * 2 + 1] = (float)pr[1];
    __syncthreads();
    float t10[10];
#pragma unroll
    for (int j = 0; j < 10; ++j) t10[j] = NEG_INF;
    for (int i = 0; i < 128; ++i) {
      int col = lane + i * 64;
      if (col == brow) continue;
      const bf16x8* cp = (const bf16x8*)(an + (size_t)col * ND);
      float d = 0.f;
#pragma unroll
      for (int k = 0; k < 16; ++k) {
        bf16x8 p = cp[k];
#pragma unroll
        for (int e = 0; e < 8; ++e) d = fmaf(rv[k * 8 + e], (float)p[e], d);
      }
      if (d > t10[0]) insert10(t10, d);
    }
#pragma unroll
    for (int j = 0; j < 10; ++j) lst[lane][j] = t10[j];
    __syncthreads();
    if (lane == 0) {
      float cur[10];
#pragma unroll
      for (int j = 0; j < 10; ++j) cur[j] = lst[0][j];
      for (int s = 1; s < 64; ++s)
        for (int j = 0; j < 10; ++j) {
          float v = lst[s][j];
          if (v > cur[0]) insert10(cur, v);
        }
      float x[11];
#pragma unroll
      for (int j = 0; j < 10; ++j) x[j] = cur[j];
      x[10] = pos[brow];
      atomicAdd(out, row_loss(x) * (-1.f / (2.f * (float)NB * 11.f)));
    }
    __syncthreads();
  }
}

// ---------------------------------------------------------------------------
// ws: [an bf16 4MB][pos 32KB][tk 2.62MB][cnth 256KB][taug 2KB] ~= 7.0 MB.
// 3 nodes, no memsets: knorm zeroes d_out; cnth/taug written unconditionally.
// ---------------------------------------------------------------------------
extern "C" void kernel_launch(void* const* d_in, const int* in_sizes, int n_in,
                              void* d_out, int out_size, void* d_ws, size_t ws_size,
                              hipStream_t stream) {
  const float* aug1 = (const float*)d_in[0];
  const float* aug2 = (const float*)d_in[1];
  char* w = (char*)d_ws;
  __bf16* an = (__bf16*)w;
  float* pos = (float*)(w + (size_t)4 * 1024 * 1024);
  float* tk = pos + NB;
  int* cnth = (int*)(tk + (size_t)2 * NB * 40);
  float* taug = (float*)(cnth + (size_t)2 * NB * 4);

  knorm<<<dim3(NB / 4), dim3(256), 0, stream>>>(aug1, aug2, an, pos, (float*)d_out);
  kgram<<<dim3(256, 2), dim3(256), 0, stream>>>(an, tk, cnth, taug);
  ksort<<<dim3(2 * NB / 64), dim3(64), 0, stream>>>(tk, pos, cnth, taug, an, (float*)d_out);
}